// Round 12
// baseline (395.850 us; speedup 1.0000x reference)
//
#include <hip/hip_runtime.h>
#include <math.h>

#define VRX 100
#define NZ 80
#define SLAB_CELLS (VRX*NZ)       /* 8000 floats = 32 KB */
#define GRID_CELLS (VRX*VRX*NZ)   /* 800000 */
#define NPIX (1024*1024)
#define MC 960
#define MAP_ELEMS (MC*MC)

/* ws layout (floats):
   [0, 20000)        fp maps: ch0 fp_map then ch1 fp_exp, each 100x100
   [20000, 20008)    params: cth, sth, sx, sy, ca, sa
   [20032, 282176)   xbin: 1 MB per-pixel x-slab keys (uint8, 8B-aligned)
   [282176, ...)     NP replicas of the 800000-float voxel grid (16B-aligned)
*/

__device__ __forceinline__ void compute_pos(int i, int j, float d,
                                            float ca, float sa, float* pos) {
    float X = ((float)j - 511.5f) * d / 512.0f;
    float Z = ((float)(1023 - i) - 511.5f) * d / 512.0f;
    float Y = d;
    float x1 = X;
    float y1 = ca*Y - sa*Z;
    float z1 = (sa*Y + ca*Z) + 88.0f;
    const float CB = 6.123233995736766e-17f;
    float x2 = (CB*x1 + y1) + 250.0f;
    float y2 = (-x1) + CB*y1;
    float z2 = z1;
    float cx = (x2/5.0f - 50.0f)/100.0f*2.0f;
    float cy = (y2/5.0f - 50.0f)/100.0f*2.0f;
    float cz = (z2/5.0f - 32.0f)/80.0f*2.0f;
    pos[0] = cx*50.0f + 50.0f;
    pos[1] = cy*50.0f + 50.0f;
    pos[2] = cz*40.0f + 40.0f;
}

__global__ void pose_kernel(const float* __restrict__ pose_obs,
                            const float* __restrict__ poses_last,
                            const int* __restrict__ elev,
                            float* __restrict__ params,
                            float* __restrict__ out_cur) {
    float th = poses_last[2] / 57.29577951308232f;
    float s = sinf(th), c = cosf(th);
    float ny = (poses_last[1] + pose_obs[0]*s) + pose_obs[1]*c;
    float nx = (poses_last[0] + pose_obs[0]*c) - pose_obs[1]*s;
    float nt = poses_last[2] + pose_obs[2]*57.29577951308232f;
    nt = fmodf(nt - 180.0f, 360.0f) + 180.0f;
    nt = fmodf(nt + 180.0f, 360.0f) - 180.0f;
    out_cur[0] = nx; out_cur[1] = ny; out_cur[2] = nt;
    out_cur[3] = nx; out_cur[4] = ny; out_cur[5] = nt;

    float spx = -((nx*100.0f)/5.0f - 480.0f)/480.0f;
    float spy = -((ny*100.0f)/5.0f - 480.0f)/480.0f;
    float tdeg = nt - 180.0f;
    float trad = (tdeg * (float)M_PI) / 180.0f;
    params[0] = cosf(trad);
    params[1] = sinf(trad);
    params[2] = spy;   /* x-offset of trans grid (st[:,0] = sp reversed) */
    params[3] = spx;   /* y-offset */
    double a = (double)elev[0] * (M_PI/180.0);
    params[4] = (float)cos(a);
    params[5] = (float)sin(a);
}

/* per-pixel x-slab key */
__global__ void binkey_kernel(const float* __restrict__ depth,
                              const float* __restrict__ params,
                              unsigned char* __restrict__ xbin) {
    int n = blockIdx.x*blockDim.x + threadIdx.x;
    if (n >= NPIX) return;
    int i = n >> 10, j = n & 1023;
    float pos[3];
    compute_pos(i, j, depth[n], params[4], params[5], pos);
    float fl = floorf(pos[0]);
    xbin[n] = (fl >= 0.0f && fl <= 99.0f) ? (unsigned char)(int)fl : 0xFF;
}

__device__ __forceinline__ bool has_byte(unsigned long long v, unsigned int b) {
    unsigned long long x = v ^ (0x0101010101010101ULL * (unsigned long long)b);
    return ((x - 0x0101010101010101ULL) & ~x & 0x8080808080808080ULL) != 0ULL;
}

/* block (b,p): accumulate x-cell b's y-z slab from pixel partition p into
   32 KB LDS (LDS atomics only), then flush as plain coalesced writes to
   replica p. Grid fully overwritten each call -> no memset needed. */
__global__ void slab_kernel(const float* __restrict__ depth,
                            const float* __restrict__ feat,
                            const unsigned char* __restrict__ xbin,
                            const float* __restrict__ params,
                            float* __restrict__ grids, int NP) {
    __shared__ float slab[SLAB_CELLS];
    int b = blockIdx.x % 100;
    int p = blockIdx.x / 100;
    int tid = threadIdx.x;

    for (int i = tid; i < SLAB_CELLS; i += 256) slab[i] = 0.0f;
    __syncthreads();

    if (b > 0) {
        float ca = params[4], sa = params[5];
        unsigned int bm1 = (unsigned int)(b - 1), bb = (unsigned int)b;
        const unsigned long long* xb64 = (const unsigned long long*)xbin;
        int words = (NPIX/8)/NP;
        int w0 = p*words;
        for (int idx = w0 + tid; idx < w0 + words; idx += 256) {
            unsigned long long v = xb64[idx];
            if (!(has_byte(v, bm1) | has_byte(v, bb))) continue;
            for (int by = 0; by < 8; ++by) {
                unsigned int key = (unsigned int)((v >> (8*by)) & 0xFFULL);
                if (key != bm1 && key != bb) continue;
                int n = (idx << 3) + by;
                int i = n >> 10, j = n & 1023;
                float d = depth[n];
                float pos[3];
                compute_pos(i, j, d, ca, sa, pos);
                /* target cell b; weight vs recomputed pos (|pos0-b|<1) */
                float wx = 1.0f - fabsf(pos[0] - (float)b);
                float fly = floorf(pos[1]);
                float flz = floorf(pos[2]);
                float wyv[2]; int iyv[2];
#pragma unroll
                for (int o = 0; o < 2; ++o) {
                    float pp = fly + (float)o;
                    bool s = (pp > 0.0f) && (pp < 100.0f);
                    wyv[o] = s ? (1.0f - fabsf(pos[1] - pp)) : 0.0f;
                    iyv[o] = s ? (int)pp : 0;
                }
                float wzv[2]; int izv[2];
#pragma unroll
                for (int o = 0; o < 2; ++o) {
                    float pp = flz + (float)o;
                    bool s = (pp > 0.0f) && (pp < 80.0f);
                    wzv[o] = s ? (1.0f - fabsf(pos[2] - pp)) : 0.0f;
                    izv[o] = s ? (int)pp : 0;
                }
                float fv = feat[n];
#pragma unroll
                for (int o1 = 0; o1 < 2; ++o1)
#pragma unroll
                for (int o2 = 0; o2 < 2; ++o2) {
                    float w = (wx*wyv[o1])*wzv[o2];
                    if (w != 0.0f) atomicAdd(&slab[iyv[o1]*80 + izv[o2]], fv*w);
                }
            }
        }
    }
    __syncthreads();

    float4* dst = (float4*)(grids + (size_t)p*GRID_CELLS + b*SLAB_CELLS);
    const float4* src = (const float4*)slab;
    for (int i = tid; i < SLAB_CELLS/4; i += 256) dst[i] = src[i];
}

/* 4 threads per output column; float4 z-loads; sums NP replicas before
   rint; 4-lane shuffle combine of integer-valued partials (exact). */
__global__ void reduce_kernel(const float* __restrict__ grids, int NP,
                              float* __restrict__ fp,
                              float* __restrict__ out_fpmap) {
    int tq = blockIdx.x*blockDim.x + threadIdx.x;
    if (tq >= 40000) return;
    int col = tq >> 2, q = tq & 3;
    int r = col / 100, cc = col % 100;
    int base = (cc*100 + (99 - r))*80 + q*20;
    float4 a[5];
#pragma unroll
    for (int v4 = 0; v4 < 5; ++v4) a[v4] = make_float4(0.f, 0.f, 0.f, 0.f);
    for (int rep = 0; rep < NP; ++rep) {
        const float4* g4 = (const float4*)(grids + (size_t)rep*GRID_CELLS + base);
#pragma unroll
        for (int v4 = 0; v4 < 5; ++v4) {
            float4 v = g4[v4];
            a[v4].x += v.x; a[v4].y += v.y; a[v4].z += v.z; a[v4].w += v.w;
        }
    }
    float s_all = 0.0f, s_mid = 0.0f;
#pragma unroll
    for (int v4 = 0; v4 < 5; ++v4) {
        float vals[4] = {a[v4].x, a[v4].y, a[v4].z, a[v4].w};
#pragma unroll
        for (int e = 0; e < 4; ++e) {
            float rv = rintf(vals[e]);    /* jnp.round = half-to-even */
            s_all += rv;
            int k = q*20 + v4*4 + e;
            if (k >= 13 && k < 25) s_mid += rv;
        }
    }
    s_all += __shfl_xor(s_all, 1); s_all += __shfl_xor(s_all, 2);
    s_mid += __shfl_xor(s_mid, 1); s_mid += __shfl_xor(s_mid, 2);
    if (q == 0) {
        float fpm = fminf(fmaxf(s_mid, 0.0f), 1.0f);
        float fpe = fminf(fmaxf(s_all, 0.0f), 1.0f);
        fp[col] = fpm;
        fp[10000 + col] = fpe;
        out_fpmap[col] = fpm;
    }
}

__device__ __forceinline__ float av_at(const float* __restrict__ fp, int c, int yy, int xx) {
    if (yy >= 380 && yy < 480 && xx >= 430 && xx < 530)
        return fp[c*10000 + (yy-380)*100 + (xx-430)];
    return 0.0f;
}

__device__ __forceinline__ float samp_av(const float* __restrict__ fp, int c,
                                         float ixf, float iyf) {
    if (ixf >= 0.0f && ixf < 960.0f && iyf >= 0.0f && iyf < 960.0f)
        return av_at(fp, c, (int)iyf, (int)ixf);
    return 0.0f;
}

__device__ float rot_sample(const float* __restrict__ fp, int c, int ii, int jj,
                            float cth, float sth) {
    float gxx = ((float)jj*2.0f + 1.0f)/960.0f - 1.0f;
    float gyy = ((float)ii*2.0f + 1.0f)/960.0f - 1.0f;
    float rx = cth*gxx + (-sth)*gyy;
    float ry = sth*gxx + cth*gyy;
    float x = (rx + 1.0f)*0.5f*959.0f;
    float y = (ry + 1.0f)*0.5f*959.0f;
    float x0 = floorf(x), y0 = floorf(y);
    float wx = x - x0, wy = y - y0;
    float acc;
    acc =       samp_av(fp,c,x0,     y0     )*(1.0f-wx)*(1.0f-wy);
    acc = acc + samp_av(fp,c,x0+1.0f,y0     )*wx       *(1.0f-wy);
    acc = acc + samp_av(fp,c,x0,     y0+1.0f)*(1.0f-wx)*wy;
    acc = acc + samp_av(fp,c,x0+1.0f,y0+1.0f)*wx       *wy;
    return acc;
}

__device__ __forceinline__ float samp_rot(const float* __restrict__ fp, int c,
                                          float ixf, float iyf, float cth, float sth) {
    if (ixf >= 0.0f && ixf < 960.0f && iyf >= 0.0f && iyf < 960.0f)
        return rot_sample(fp, c, (int)iyf, (int)ixf, cth, sth);
    return 0.0f;
}

__global__ void trans_kernel(const float* __restrict__ fp,
                             const float* __restrict__ params,
                             const float* __restrict__ maps_last,
                             float* __restrict__ out_map) {
    int t = blockIdx.x*blockDim.x + threadIdx.x;
    if (t >= 2*MAP_ELEMS) return;
    int c = t / MAP_ELEMS;
    int rem = t - c*MAP_ELEMS;
    int i = rem / MC, j = rem - (rem / MC)*MC;
    float cth = params[0], sth = params[1], sx = params[2], sy = params[3];

    float gx = ((float)j*2.0f + 1.0f)/960.0f - 1.0f;
    float gy = ((float)i*2.0f + 1.0f)/960.0f - 1.0f;
    float tx = gx + sx;
    float ty = gy + sy;
    float x = (tx + 1.0f)*0.5f*959.0f;
    float y = (ty + 1.0f)*0.5f*959.0f;

    /* early-out: rigid map of the continuous sample point; outside a ~4.4 px
       margin of the active 100x100 window all 16 texels are provably zero. */
    float gxc = (2.0f*x + 1.0f)/960.0f - 1.0f;
    float gyc = (2.0f*y + 1.0f)/960.0f - 1.0f;
    float rxc = cth*gxc - sth*gyc;
    float ryc = sth*gxc + cth*gyc;
    float pxc = (rxc + 1.0f)*0.5f*959.0f;
    float pyc = (ryc + 1.0f)*0.5f*959.0f;
    bool heavy = (pxc >= 425.0f) && (pxc <= 535.0f) &&
                 (pyc >= 375.0f) && (pyc <= 485.0f);

    float acc = 0.0f;
    if (heavy) {
        float x0 = floorf(x), y0 = floorf(y);
        float wx = x - x0, wy = y - y0;
        acc =       samp_rot(fp,c,x0,     y0,     cth,sth)*(1.0f-wx)*(1.0f-wy);
        acc = acc + samp_rot(fp,c,x0+1.0f,y0,     cth,sth)*wx       *(1.0f-wy);
        acc = acc + samp_rot(fp,c,x0,     y0+1.0f,cth,sth)*(1.0f-wx)*wy;
        acc = acc + samp_rot(fp,c,x0+1.0f,y0+1.0f,cth,sth)*wx       *wy;
    }
    out_map[t] = fmaxf(maps_last[t], acc);
}

extern "C" void kernel_launch(void* const* d_in, const int* in_sizes, int n_in,
                              void* d_out, int out_size, void* d_ws, size_t ws_size,
                              hipStream_t stream) {
    const float* depth      = (const float*)d_in[0];
    const float* pose_obs   = (const float*)d_in[1];
    const float* maps_last  = (const float*)d_in[2];
    const float* poses_last = (const float*)d_in[3];
    const float* feat       = (const float*)d_in[4];
    const int*   elev       = (const int*)d_in[5];
    float* out = (float*)d_out;

    float* fp     = (float*)d_ws;                       /* 20000 floats */
    float* params = fp + 20000;                         /* 8 floats     */
    unsigned char* xbin = (unsigned char*)(fp + 20032); /* 1 MB         */
    float* grids  = fp + 282176;                        /* NP * 800000  */

    /* largest power-of-2 partition/replica count that fits (>=1) */
    size_t avail = ws_size / sizeof(float);
    int NP = 1;
    while (NP < 8 && (size_t)282176 + (size_t)GRID_CELLS*(size_t)(NP*2) <= avail)
        NP *= 2;

    pose_kernel<<<1, 1, 0, stream>>>(pose_obs, poses_last, elev, params,
                                     out + 10000 + 2*MAP_ELEMS);
    binkey_kernel<<<(NPIX+255)/256, 256, 0, stream>>>(depth, params, xbin);
    slab_kernel<<<100*NP, 256, 0, stream>>>(depth, feat, xbin, params, grids, NP);
    reduce_kernel<<<(40000+255)/256, 256, 0, stream>>>(grids, NP, fp, out);
    trans_kernel<<<(2*MAP_ELEMS+255)/256, 256, 0, stream>>>(fp, params, maps_last,
                                                            out + 10000);
}

// Round 15
// 204.616 us; speedup vs baseline: 1.9346x; 1.9346x over previous
//
#include <hip/hip_runtime.h>
#include <math.h>

#define VRX 100
#define NZ 80
#define SLAB_CELLS (VRX*NZ)       /* 8000 floats = 32 KB */
#define GRID_CELLS (VRX*VRX*NZ)   /* 800000 */
#define NPIX (1024*1024)
#define MC 960
#define MAP_ELEMS (MC*MC)
#define QSIZE 4096                /* LDS compaction queue entries */

/* ws layout (floats):
   [0, 20000)        fp maps: ch0 fp_map then ch1 fp_exp, each 100x100
   [20000, 20008)    params: cth, sth, sx, sy, ca, sa
   [20032, 282176)   xbin: 1 MB per-pixel x-slab keys (uint8, 8B-aligned)
   [282176, ...)     NP replicas of the 800000-float voxel grid (16B-aligned)
*/

__device__ __forceinline__ void compute_pos(int i, int j, float d,
                                            float ca, float sa, float* pos) {
    float X = ((float)j - 511.5f) * d / 512.0f;
    float Z = ((float)(1023 - i) - 511.5f) * d / 512.0f;
    float Y = d;
    float x1 = X;
    float y1 = ca*Y - sa*Z;
    float z1 = (sa*Y + ca*Z) + 88.0f;
    const float CB = 6.123233995736766e-17f;
    float x2 = (CB*x1 + y1) + 250.0f;
    float y2 = (-x1) + CB*y1;
    float z2 = z1;
    float cx = (x2/5.0f - 50.0f)/100.0f*2.0f;
    float cy = (y2/5.0f - 50.0f)/100.0f*2.0f;
    float cz = (z2/5.0f - 32.0f)/80.0f*2.0f;
    pos[0] = cx*50.0f + 50.0f;
    pos[1] = cy*50.0f + 50.0f;
    pos[2] = cz*40.0f + 40.0f;
}

__global__ void pose_kernel(const float* __restrict__ pose_obs,
                            const float* __restrict__ poses_last,
                            const int* __restrict__ elev,
                            float* __restrict__ params,
                            float* __restrict__ out_cur) {
    float th = poses_last[2] / 57.29577951308232f;
    float s = sinf(th), c = cosf(th);
    float ny = (poses_last[1] + pose_obs[0]*s) + pose_obs[1]*c;
    float nx = (poses_last[0] + pose_obs[0]*c) - pose_obs[1]*s;
    float nt = poses_last[2] + pose_obs[2]*57.29577951308232f;
    nt = fmodf(nt - 180.0f, 360.0f) + 180.0f;
    nt = fmodf(nt + 180.0f, 360.0f) - 180.0f;
    out_cur[0] = nx; out_cur[1] = ny; out_cur[2] = nt;
    out_cur[3] = nx; out_cur[4] = ny; out_cur[5] = nt;

    float spx = -((nx*100.0f)/5.0f - 480.0f)/480.0f;
    float spy = -((ny*100.0f)/5.0f - 480.0f)/480.0f;
    float tdeg = nt - 180.0f;
    float trad = (tdeg * (float)M_PI) / 180.0f;
    params[0] = cosf(trad);
    params[1] = sinf(trad);
    params[2] = spy;   /* x-offset of trans grid (st[:,0] = sp reversed) */
    params[3] = spx;   /* y-offset */
    double a = (double)elev[0] * (M_PI/180.0);
    params[4] = (float)cos(a);
    params[5] = (float)sin(a);
}

/* per-pixel x-slab key */
__global__ void binkey_kernel(const float* __restrict__ depth,
                              const float* __restrict__ params,
                              unsigned char* __restrict__ xbin) {
    int n = blockIdx.x*blockDim.x + threadIdx.x;
    if (n >= NPIX) return;
    int i = n >> 10, j = n & 1023;
    float pos[3];
    compute_pos(i, j, depth[n], params[4], params[5], pos);
    float fl = floorf(pos[0]);
    xbin[n] = (fl >= 0.0f && fl <= 99.0f) ? (unsigned char)(int)fl : 0xFF;
}

__device__ __forceinline__ bool has_byte(unsigned long long v, unsigned int b) {
    unsigned long long x = v ^ (0x0101010101010101ULL * (unsigned long long)b);
    return ((x - 0x0101010101010101ULL) & ~x & 0x8080808080808080ULL) != 0ULL;
}

/* block (b,p): scan partition p's keys, COMPACT matching pixel indices into
   an LDS queue, drain dense (all 256 lanes) into the 32 KB LDS slab via LDS
   atomics, then flush as plain coalesced writes to replica p. */
__global__ void slab_kernel(const float* __restrict__ depth,
                            const float* __restrict__ feat,
                            const unsigned char* __restrict__ xbin,
                            const float* __restrict__ params,
                            float* __restrict__ grids, int NP) {
    __shared__ float slab[SLAB_CELLS];
    __shared__ int   queue[QSIZE];
    __shared__ int   qcnt;
    int b = blockIdx.x % 100;
    int p = blockIdx.x / 100;
    int tid = threadIdx.x;

    for (int i = tid; i < SLAB_CELLS; i += 256) slab[i] = 0.0f;
    if (tid == 0) qcnt = 0;
    __syncthreads();

    if (b > 0) {
        float ca = params[4], sa = params[5];
        unsigned int bm1 = (unsigned int)(b - 1), bb = (unsigned int)b;
        const unsigned long long* xb64 = (const unsigned long long*)xbin;
        int words = (NPIX/8)/NP;        /* divisible by 256 for NP in {1,2,4,8} */
        int w0 = p*words;
        int nit = words/256;
        for (int it = 0; it < nit; ++it) {
            int idx = w0 + it*256 + tid;
            unsigned long long v = xb64[idx];
            if (has_byte(v, bm1) | has_byte(v, bb)) {
#pragma unroll
                for (int by = 0; by < 8; ++by) {
                    unsigned int key = (unsigned int)((v >> (8*by)) & 0xFFULL);
                    if (key == bm1 || key == bb) {
                        int pos = atomicAdd(&qcnt, 1);
                        queue[pos] = (idx << 3) + by;
                    }
                }
            }
            __syncthreads();
            if (qcnt >= QSIZE - 2048 || it == nit-1) {   /* uniform decision */
                int cnt = qcnt;
                for (int q = tid; q < cnt; q += 256) {
                    int n = queue[q];
                    int i = n >> 10, j = n & 1023;
                    float d = depth[n];
                    float pos[3];
                    compute_pos(i, j, d, ca, sa, pos);
                    /* target cell b; weight vs recomputed pos (|pos0-b|<1) */
                    float wx = 1.0f - fabsf(pos[0] - (float)b);
                    float fly = floorf(pos[1]);
                    float flz = floorf(pos[2]);
                    float wyv[2]; int iyv[2];
#pragma unroll
                    for (int o = 0; o < 2; ++o) {
                        float pp = fly + (float)o;
                        bool s = (pp > 0.0f) && (pp < 100.0f);
                        wyv[o] = s ? (1.0f - fabsf(pos[1] - pp)) : 0.0f;
                        iyv[o] = s ? (int)pp : 0;
                    }
                    float wzv[2]; int izv[2];
#pragma unroll
                    for (int o = 0; o < 2; ++o) {
                        float pp = flz + (float)o;
                        bool s = (pp > 0.0f) && (pp < 80.0f);
                        wzv[o] = s ? (1.0f - fabsf(pos[2] - pp)) : 0.0f;
                        izv[o] = s ? (int)pp : 0;
                    }
                    float fv = feat[n];
#pragma unroll
                    for (int o1 = 0; o1 < 2; ++o1)
#pragma unroll
                    for (int o2 = 0; o2 < 2; ++o2) {
                        float w = (wx*wyv[o1])*wzv[o2];
                        if (w != 0.0f) atomicAdd(&slab[iyv[o1]*80 + izv[o2]], fv*w);
                    }
                }
                __syncthreads();
                if (tid == 0) qcnt = 0;
                __syncthreads();
            }
        }
    }
    __syncthreads();

    float4* dst = (float4*)(grids + (size_t)p*GRID_CELLS + b*SLAB_CELLS);
    const float4* src = (const float4*)slab;
    for (int i = tid; i < SLAB_CELLS/4; i += 256) dst[i] = src[i];
}

/* 4 threads per output column; float4 z-loads; sums NP replicas before
   rint; 4-lane shuffle combine of integer-valued partials (exact). */
__global__ void reduce_kernel(const float* __restrict__ grids, int NP,
                              float* __restrict__ fp,
                              float* __restrict__ out_fpmap) {
    int tq = blockIdx.x*blockDim.x + threadIdx.x;
    if (tq >= 40000) return;
    int col = tq >> 2, q = tq & 3;
    int r = col / 100, cc = col % 100;
    int base = (cc*100 + (99 - r))*80 + q*20;
    float4 a[5];
#pragma unroll
    for (int v4 = 0; v4 < 5; ++v4) a[v4] = make_float4(0.f, 0.f, 0.f, 0.f);
    for (int rep = 0; rep < NP; ++rep) {
        const float4* g4 = (const float4*)(grids + (size_t)rep*GRID_CELLS + base);
#pragma unroll
        for (int v4 = 0; v4 < 5; ++v4) {
            float4 v = g4[v4];
            a[v4].x += v.x; a[v4].y += v.y; a[v4].z += v.z; a[v4].w += v.w;
        }
    }
    float s_all = 0.0f, s_mid = 0.0f;
#pragma unroll
    for (int v4 = 0; v4 < 5; ++v4) {
        float vals[4] = {a[v4].x, a[v4].y, a[v4].z, a[v4].w};
#pragma unroll
        for (int e = 0; e < 4; ++e) {
            float rv = rintf(vals[e]);    /* jnp.round = half-to-even */
            s_all += rv;
            int k = q*20 + v4*4 + e;
            if (k >= 13 && k < 25) s_mid += rv;
        }
    }
    s_all += __shfl_xor(s_all, 1); s_all += __shfl_xor(s_all, 2);
    s_mid += __shfl_xor(s_mid, 1); s_mid += __shfl_xor(s_mid, 2);
    if (q == 0) {
        float fpm = fminf(fmaxf(s_mid, 0.0f), 1.0f);
        float fpe = fminf(fmaxf(s_all, 0.0f), 1.0f);
        fp[col] = fpm;
        fp[10000 + col] = fpe;
        out_fpmap[col] = fpm;
    }
}

__device__ __forceinline__ float av_at(const float* __restrict__ fp, int c, int yy, int xx) {
    if (yy >= 380 && yy < 480 && xx >= 430 && xx < 530)
        return fp[c*10000 + (yy-380)*100 + (xx-430)];
    return 0.0f;
}

__device__ __forceinline__ float samp_av(const float* __restrict__ fp, int c,
                                         float ixf, float iyf) {
    if (ixf >= 0.0f && ixf < 960.0f && iyf >= 0.0f && iyf < 960.0f)
        return av_at(fp, c, (int)iyf, (int)ixf);
    return 0.0f;
}

__device__ float rot_sample(const float* __restrict__ fp, int c, int ii, int jj,
                            float cth, float sth) {
    float gxx = ((float)jj*2.0f + 1.0f)/960.0f - 1.0f;
    float gyy = ((float)ii*2.0f + 1.0f)/960.0f - 1.0f;
    float rx = cth*gxx + (-sth)*gyy;
    float ry = sth*gxx + cth*gyy;
    float x = (rx + 1.0f)*0.5f*959.0f;
    float y = (ry + 1.0f)*0.5f*959.0f;
    float x0 = floorf(x), y0 = floorf(y);
    float wx = x - x0, wy = y - y0;
    float acc;
    acc =       samp_av(fp,c,x0,     y0     )*(1.0f-wx)*(1.0f-wy);
    acc = acc + samp_av(fp,c,x0+1.0f,y0     )*wx       *(1.0f-wy);
    acc = acc + samp_av(fp,c,x0,     y0+1.0f)*(1.0f-wx)*wy;
    acc = acc + samp_av(fp,c,x0+1.0f,y0+1.0f)*wx       *wy;
    return acc;
}

__device__ __forceinline__ float samp_rot(const float* __restrict__ fp, int c,
                                          float ixf, float iyf, float cth, float sth) {
    if (ixf >= 0.0f && ixf < 960.0f && iyf >= 0.0f && iyf < 960.0f)
        return rot_sample(fp, c, (int)iyf, (int)ixf, cth, sth);
    return 0.0f;
}

__global__ void trans_kernel(const float* __restrict__ fp,
                             const float* __restrict__ params,
                             const float* __restrict__ maps_last,
                             float* __restrict__ out_map) {
    int t = blockIdx.x*blockDim.x + threadIdx.x;
    if (t >= 2*MAP_ELEMS) return;
    int c = t / MAP_ELEMS;
    int rem = t - c*MAP_ELEMS;
    int i = rem / MC, j = rem - (rem / MC)*MC;
    float cth = params[0], sth = params[1], sx = params[2], sy = params[3];

    float gx = ((float)j*2.0f + 1.0f)/960.0f - 1.0f;
    float gy = ((float)i*2.0f + 1.0f)/960.0f - 1.0f;
    float tx = gx + sx;
    float ty = gy + sy;
    float x = (tx + 1.0f)*0.5f*959.0f;
    float y = (ty + 1.0f)*0.5f*959.0f;

    /* early-out: rigid map of the continuous sample point; outside a ~4.4 px
       margin of the active 100x100 window all 16 texels are provably zero. */
    float gxc = (2.0f*x + 1.0f)/960.0f - 1.0f;
    float gyc = (2.0f*y + 1.0f)/960.0f - 1.0f;
    float rxc = cth*gxc - sth*gyc;
    float ryc = sth*gxc + cth*gyc;
    float pxc = (rxc + 1.0f)*0.5f*959.0f;
    float pyc = (ryc + 1.0f)*0.5f*959.0f;
    bool heavy = (pxc >= 425.0f) && (pxc <= 535.0f) &&
                 (pyc >= 375.0f) && (pyc <= 485.0f);

    float acc = 0.0f;
    if (heavy) {
        float x0 = floorf(x), y0 = floorf(y);
        float wx = x - x0, wy = y - y0;
        acc =       samp_rot(fp,c,x0,     y0,     cth,sth)*(1.0f-wx)*(1.0f-wy);
        acc = acc + samp_rot(fp,c,x0+1.0f,y0,     cth,sth)*wx       *(1.0f-wy);
        acc = acc + samp_rot(fp,c,x0,     y0+1.0f,cth,sth)*(1.0f-wx)*wy;
        acc = acc + samp_rot(fp,c,x0+1.0f,y0+1.0f,cth,sth)*wx       *wy;
    }
    out_map[t] = fmaxf(maps_last[t], acc);
}

extern "C" void kernel_launch(void* const* d_in, const int* in_sizes, int n_in,
                              void* d_out, int out_size, void* d_ws, size_t ws_size,
                              hipStream_t stream) {
    const float* depth      = (const float*)d_in[0];
    const float* pose_obs   = (const float*)d_in[1];
    const float* maps_last  = (const float*)d_in[2];
    const float* poses_last = (const float*)d_in[3];
    const float* feat       = (const float*)d_in[4];
    const int*   elev       = (const int*)d_in[5];
    float* out = (float*)d_out;

    float* fp     = (float*)d_ws;                       /* 20000 floats */
    float* params = fp + 20000;                         /* 8 floats     */
    unsigned char* xbin = (unsigned char*)(fp + 20032); /* 1 MB         */
    float* grids  = fp + 282176;                        /* NP * 800000  */

    /* largest power-of-2 partition/replica count that fits (>=1) */
    size_t avail = ws_size / sizeof(float);
    int NP = 1;
    while (NP < 8 && (size_t)282176 + (size_t)GRID_CELLS*(size_t)(NP*2) <= avail)
        NP *= 2;

    pose_kernel<<<1, 1, 0, stream>>>(pose_obs, poses_last, elev, params,
                                     out + 10000 + 2*MAP_ELEMS);
    binkey_kernel<<<(NPIX+255)/256, 256, 0, stream>>>(depth, params, xbin);
    slab_kernel<<<100*NP, 256, 0, stream>>>(depth, feat, xbin, params, grids, NP);
    reduce_kernel<<<(40000+255)/256, 256, 0, stream>>>(grids, NP, fp, out);
    trans_kernel<<<(2*MAP_ELEMS+255)/256, 256, 0, stream>>>(fp, params, maps_last,
                                                            out + 10000);
}